// Round 2
// baseline (279.253 us; speedup 1.0000x reference)
//
#include <hip/hip_runtime.h>

#define BATCH 64
#define M_GT  100
#define M1    101
#define NANCH 8732
#define BLOCK 256
#define NPT   2                    // anchors per thread -> dwordx2 stores
#define NTILE (BLOCK * NPT)        // 512
#define NX    18                   // ceil(8732/512)
#define NBLK  (NX * BATCH)         // 1152 blocks = 4608 waves = 4.5/SIMD
#define GROUP 8                    // rows per store burst
#define MBULK ((M1 / GROUP) * GROUP)   // 96
#define MTAIL (M1 - MBULK)             // 5

// ext_vector types so __builtin_nontemporal_store accepts them
typedef float f32x2 __attribute__((ext_vector_type(2)));

// Single fused dispatch. Each block builds the 101-row GT table in LDS
// (redundant across blocks but L2-served, ~1 µs total). Masking: pad row
// (m=0) and invalid rows (cls==0) get area=+inf -> iou = inter*rcp(inf) = +0
// exactly, never NaN.
//
// R2: nontemporal stores. R1 (store-depth-8, 2x waves) was neutral vs R0
// -> the write limiter is invariant to per-wave store depth / wave count.
// Remaining store-path candidate: write-allocate thrash (226MB out_ious
// nearly fills the 256MB L3; allocate+evict backpressure). Outputs are
// never re-read by this kernel -> `nt` stores (bypass allocation) are
// semantically free. Decisive single-variable test.
__global__ __launch_bounds__(BLOCK) void encode_fused(
    const float* __restrict__ labels,   // [B, M, 5]
    const float* __restrict__ dboxes,   // [N, 4]
    float* __restrict__ out_labeled,    // [B, N, 5]
    float* __restrict__ out_ious)       // [B, M1, N]
{
    __shared__ float4 s_box[M1];        // {x1,y1,x2,y2}
    __shared__ float  s_ar[M1], s_cls[M1];

    const int tid = threadIdx.x;
    const int b   = blockIdx.x / NX;
    const int nb  = blockIdx.x % NX;

    if (tid < M1) {
        float x1 = 0.f, y1 = 0.f, x2 = 0.f, y2 = 0.f, cls = 0.f;
        float ar = __builtin_inff();
        if (tid >= 1) {
            const float* row = labels + ((size_t)b * M_GT + (tid - 1)) * 5;
            x1 = row[0]; y1 = row[1]; x2 = row[2]; y2 = row[3]; cls = row[4];
            if (cls != 0.0f) ar = (x2 - x1) * (y2 - y1);
        }
        s_box[tid] = make_float4(x1, y1, x2, y2);
        s_ar[tid] = ar; s_cls[tid] = cls;
    }
    __syncthreads();

    const int n0 = nb * NTILE + tid * NPT;
    if (n0 >= NANCH) return;           // NANCH % 2 == 0 -> whole pair in/out

    float ax1[NPT], ay1[NPT], ax2[NPT], ay2[NPT], aa[NPT];
    #pragma unroll
    for (int i = 0; i < NPT; ++i) {
        const float4 d = *reinterpret_cast<const float4*>(dboxes + (size_t)(n0 + i) * 4);
        ax1[i] = d.x; ay1[i] = d.y; ax2[i] = d.z; ay2[i] = d.w;
        aa[i]  = (d.z - d.x) * (d.w - d.y);
    }

    float* const irow = out_ious + (size_t)b * M1 * NANCH + n0;

    // best=-1: pad rows give iou=+0; strict > = numpy first-occurrence argmax.
    float best[NPT]; int besti[NPT];
    #pragma unroll
    for (int i = 0; i < NPT; ++i) { best[i] = -1.0f; besti[i] = 0; }

    // One row: compute NPT ious, update running argmax, nt-store 8B.
    auto row_body = [&](int m) {
        const float4 g = s_box[m];      // ds_read_b128 broadcast
        const float ga = s_ar[m];       // ds_read_b32 broadcast
        float iou[NPT];
        #pragma unroll
        for (int i = 0; i < NPT; ++i) {
            const float ix1 = fmaxf(g.x, ax1[i]), iy1 = fmaxf(g.y, ay1[i]);
            const float ix2 = fminf(g.z, ax2[i]), iy2 = fminf(g.w, ay2[i]);
            const float iw = fmaxf(ix2 - ix1, 0.0f), ih = fmaxf(iy2 - iy1, 0.0f);
            const float inter = iw * ih;
            iou[i] = inter * __builtin_amdgcn_rcpf(ga + aa[i] - inter);  // validated R3/R7
            if (iou[i] > best[i]) { best[i] = iou[i]; besti[i] = m; }
        }
        f32x2 w; w.x = iou[0]; w.y = iou[1];
        __builtin_nontemporal_store(w, reinterpret_cast<f32x2*>(irow + (size_t)m * NANCH));
    };

    for (int mg = 0; mg < MBULK; mg += GROUP) {
        #pragma unroll
        for (int r = 0; r < GROUP; ++r) row_body(mg + r);
    }
    #pragma unroll
    for (int r = 0; r < MTAIL; ++r) row_body(MBULK + r);

    // Epilogue
    float lw[NPT * 5];
    #pragma unroll
    for (int i = 0; i < NPT; ++i) {
        const int idx = (best[i] > 0.5f) ? besti[i] : 0;
        float ox = 0.f, oy = 0.f, ow = 0.f, oh = 0.f, pcls = 0.f;
        if (idx != 0) {   // iou>0.5 winner is always a valid (cls!=0) row
            const float4 t = s_box[idx];
            const float aw = ax2[i] - ax1[i], ah = ay2[i] - ay1[i];
            ox = (0.5f * (t.x + t.z) - 0.5f * (ax1[i] + ax2[i])) / aw;
            oy = (0.5f * (t.y + t.w) - 0.5f * (ay1[i] + ay2[i])) / ah;
            ow = __logf((t.z - t.x) / aw);
            oh = __logf((t.w - t.y) / ah);
            pcls = s_cls[idx];
        }
        lw[i * 5 + 0] = ox; lw[i * 5 + 1] = oy; lw[i * 5 + 2] = ow;
        lw[i * 5 + 3] = oh; lw[i * 5 + 4] = pcls;
    }
    // 10 contiguous floats = 40B, 8B-aligned (n0 even) -> 5 nt dwordx2 stores
    float* lrow = out_labeled + ((size_t)b * NANCH + n0) * 5;
    #pragma unroll
    for (int k = 0; k < 5; ++k) {
        f32x2 v; v.x = lw[k * 2]; v.y = lw[k * 2 + 1];
        __builtin_nontemporal_store(v, reinterpret_cast<f32x2*>(lrow + k * 2));
    }
}

extern "C" void kernel_launch(void* const* d_in, const int* in_sizes, int n_in,
                              void* d_out, int out_size, void* d_ws, size_t ws_size,
                              hipStream_t stream) {
    const float* labels = (const float*)d_in[0];
    const float* dboxes = (const float*)d_in[1];
    float* out_labeled = (float*)d_out;
    float* out_ious    = out_labeled + (size_t)BATCH * NANCH * 5;

    encode_fused<<<dim3(NBLK), dim3(BLOCK), 0, stream>>>(labels, dboxes, out_labeled, out_ious);
}

// Round 3
// 240.378 us; speedup vs baseline: 1.1617x; 1.1617x over previous
//
#include <hip/hip_runtime.h>

#define BATCH 64
#define M_GT  100
#define M1    101
#define NANCH 8732
#define BLOCK 256
#define NPT   2                    // anchors per thread -> dwordx2 stores
#define NTILE (BLOCK * NPT)        // 512
#define NX    18                   // ceil(8732/512)
#define NBLK  (NX * BATCH)         // 1152 blocks = 4608 waves = 4.5/SIMD
#define NXCD  8
#define GROUP 8                    // rows per store burst
#define MBULK ((M1 / GROUP) * GROUP)   // 96
#define MTAIL (M1 - MBULK)             // 5

// Journal:
//  R0: NPT=4, depth~4 stores/wave, 576 blocks          -> kernel ~104 µs
//  R1: NPT=2, depth-8 store groups, 1152 blocks        -> neutral (store
//      depth / wave count invariant)
//  R2: nontemporal stores                              -> -35 µs REGRESSION
//      (L2 write-merging was load-bearing; limiter is L2->HBM drain order)
//  R3: XCD-grouping block swizzle (this). All 18 n-chunks of a given b on
//      ONE XCD, launched back-to-back, so each (b,m) 34KB row merges in a
//      single L2 and evicts as a contiguous stream (HBM row locality).
//      Work decomposition, stores, occupancy identical to R1.
__global__ __launch_bounds__(BLOCK) void encode_fused(
    const float* __restrict__ labels,   // [B, M, 5]
    const float* __restrict__ dboxes,   // [N, 4]
    float* __restrict__ out_labeled,    // [B, N, 5]
    float* __restrict__ out_ious)       // [B, M1, N]
{
    __shared__ float4 s_box[M1];        // {x1,y1,x2,y2}
    __shared__ float  s_ar[M1], s_cls[M1];

    const int tid = threadIdx.x;
    // XCD-grouping swizzle: dispatcher round-robins blockIdx across 8 XCDs
    // (i%8 -> XCD). Put all NX chunks of each b on one XCD, consecutively.
    const int x  = blockIdx.x % NXCD;        // XCD slot
    const int j  = blockIdx.x / NXCD;        // 0..143 within XCD
    const int b  = x * (BATCH / NXCD) + j / NX;
    const int nb = j % NX;

    if (tid < M1) {
        float x1 = 0.f, y1 = 0.f, x2 = 0.f, y2 = 0.f, cls = 0.f;
        float ar = __builtin_inff();
        if (tid >= 1) {
            const float* row = labels + ((size_t)b * M_GT + (tid - 1)) * 5;
            x1 = row[0]; y1 = row[1]; x2 = row[2]; y2 = row[3]; cls = row[4];
            if (cls != 0.0f) ar = (x2 - x1) * (y2 - y1);
        }
        s_box[tid] = make_float4(x1, y1, x2, y2);
        s_ar[tid] = ar; s_cls[tid] = cls;
    }
    __syncthreads();

    const int n0 = nb * NTILE + tid * NPT;
    if (n0 >= NANCH) return;           // NANCH % 2 == 0 -> whole pair in/out

    float ax1[NPT], ay1[NPT], ax2[NPT], ay2[NPT], aa[NPT];
    #pragma unroll
    for (int i = 0; i < NPT; ++i) {
        const float4 d = *reinterpret_cast<const float4*>(dboxes + (size_t)(n0 + i) * 4);
        ax1[i] = d.x; ay1[i] = d.y; ax2[i] = d.z; ay2[i] = d.w;
        aa[i]  = (d.z - d.x) * (d.w - d.y);
    }

    float* const irow = out_ious + (size_t)b * M1 * NANCH + n0;

    // best=-1: pad rows give iou=+0; strict > = numpy first-occurrence argmax.
    float best[NPT]; int besti[NPT];
    #pragma unroll
    for (int i = 0; i < NPT; ++i) { best[i] = -1.0f; besti[i] = 0; }

    // One row: compute NPT ious, update running argmax, store 8B.
    auto row_body = [&](int m) {
        const float4 g = s_box[m];      // ds_read_b128 broadcast
        const float ga = s_ar[m];       // ds_read_b32 broadcast
        float iou[NPT];
        #pragma unroll
        for (int i = 0; i < NPT; ++i) {
            const float ix1 = fmaxf(g.x, ax1[i]), iy1 = fmaxf(g.y, ay1[i]);
            const float ix2 = fminf(g.z, ax2[i]), iy2 = fminf(g.w, ay2[i]);
            const float iw = fmaxf(ix2 - ix1, 0.0f), ih = fmaxf(iy2 - iy1, 0.0f);
            const float inter = iw * ih;
            iou[i] = inter * __builtin_amdgcn_rcpf(ga + aa[i] - inter);  // validated R3/R7
            if (iou[i] > best[i]) { best[i] = iou[i]; besti[i] = m; }
        }
        float2 w; w.x = iou[0]; w.y = iou[1];
        *reinterpret_cast<float2*>(irow + (size_t)m * NANCH) = w;
    };

    for (int mg = 0; mg < MBULK; mg += GROUP) {
        #pragma unroll
        for (int r = 0; r < GROUP; ++r) row_body(mg + r);
    }
    #pragma unroll
    for (int r = 0; r < MTAIL; ++r) row_body(MBULK + r);

    // Epilogue
    float lw[NPT * 5];
    #pragma unroll
    for (int i = 0; i < NPT; ++i) {
        const int idx = (best[i] > 0.5f) ? besti[i] : 0;
        float ox = 0.f, oy = 0.f, ow = 0.f, oh = 0.f, pcls = 0.f;
        if (idx != 0) {   // iou>0.5 winner is always a valid (cls!=0) row
            const float4 t = s_box[idx];
            const float aw = ax2[i] - ax1[i], ah = ay2[i] - ay1[i];
            ox = (0.5f * (t.x + t.z) - 0.5f * (ax1[i] + ax2[i])) / aw;
            oy = (0.5f * (t.y + t.w) - 0.5f * (ay1[i] + ay2[i])) / ah;
            ow = __logf((t.z - t.x) / aw);
            oh = __logf((t.w - t.y) / ah);
            pcls = s_cls[idx];
        }
        lw[i * 5 + 0] = ox; lw[i * 5 + 1] = oy; lw[i * 5 + 2] = ow;
        lw[i * 5 + 3] = oh; lw[i * 5 + 4] = pcls;
    }
    // 10 contiguous floats = 40B, 8B-aligned (n0 even) -> 5 dwordx2 stores
    float* lrow = out_labeled + ((size_t)b * NANCH + n0) * 5;
    #pragma unroll
    for (int k = 0; k < 5; ++k) {
        float2 v; v.x = lw[k * 2]; v.y = lw[k * 2 + 1];
        *reinterpret_cast<float2*>(lrow + k * 2) = v;
    }
}

extern "C" void kernel_launch(void* const* d_in, const int* in_sizes, int n_in,
                              void* d_out, int out_size, void* d_ws, size_t ws_size,
                              hipStream_t stream) {
    const float* labels = (const float*)d_in[0];
    const float* dboxes = (const float*)d_in[1];
    float* out_labeled = (float*)d_out;
    float* out_ious    = out_labeled + (size_t)BATCH * NANCH * 5;

    encode_fused<<<dim3(NBLK), dim3(BLOCK), 0, stream>>>(labels, dboxes, out_labeled, out_ious);
}